// Round 13
// baseline (2933.077 us; speedup 1.0000x reference)
//
#include <hip/hip_runtime.h>
#include <math.h>

#define T_IN   12
#define T_OUT  12
#define NB     8192          /* 512 nodes x 16 batch, row id = n*16+b */
#define EPSV   1e-6f

typedef __attribute__((ext_vector_type(8))) short short8;
typedef __attribute__((ext_vector_type(4))) float floatx4;

// ---------------------------------------------------------------------------
// bf16 helpers. P-format: uint = (lo_bf16 << 16) | hi_bf16, value ~ hi + lo.
// ---------------------------------------------------------------------------
__device__ __forceinline__ unsigned short f2bf(float x) {     // RNE (setup packs)
    union { float f; unsigned u; } v; v.f = x;
    unsigned r = v.u + 0x7fffu + ((v.u >> 16) & 1u);
    return (unsigned short)(r >> 16);
}
__device__ __forceinline__ float bf2f(unsigned short h) {
    union { float f; unsigned u; } v; v.u = ((unsigned)h) << 16;
    return v.f;
}
__device__ __forceinline__ unsigned packbf(float v) {         // trunc split (hot path)
    unsigned u = __float_as_uint(v);
    unsigned hu = u & 0xffff0000u;
    float r = v - __uint_as_float(hu);
    unsigned ru = __float_as_uint(r);
    return (ru & 0xffff0000u) | (u >> 16);
}
__device__ __forceinline__ void split2(float v, short& h, short& l) {  // trunc split
    unsigned u = __float_as_uint(v);
    h = (short)(u >> 16);
    float r = v - __uint_as_float(u & 0xffff0000u);
    l = (short)(__float_as_uint(r) >> 16);
}

__device__ __forceinline__ float sigmoid_fast(float x) {
    return 1.0f / (1.0f + __expf(-x));
}
__device__ __forceinline__ float tanh_fast(float x) {
    float e = __expf(2.0f * x);
    return 1.0f - 2.0f / (e + 1.0f);
}

// ---------------------------------------------------------------------------
// Descriptors
// ---------------------------------------------------------------------------
struct HopA {                    // fp32 setup GEMM (W^2 build)
    const float* M[4];
    float* dst0[4];
};

struct HopM {                    // MFMA hop: Y[z] = M[z] @ X, X/Y in P-format
    const unsigned short* Ahi[4]; const unsigned short* Alo[4];
    const unsigned* src0; const unsigned* src1;
    unsigned* dst0[4]; unsigned* dst1[4];
    int tiles0;
};

struct XHopM {                   // MFMA x-hop: fp32 in/out
    const unsigned short* Ahi[4]; const unsigned short* Alo[4];
    const float* X;              // addr = (col>>4)*NB + k*16 + (col&15)
    float* Y;                    // Y[((col>>4)*4+z)*NB + m*16 + (col&15)]
    int ncols;                   // 192 (encoder all-t)
};

struct WPack { const float* w[4]; unsigned short* hi[4]; unsigned short* lo[4]; };

struct LPackAll { const float* W[6]; unsigned short* hi[6]; unsigned short* lo[6]; };

struct LinJob {                  // rz-type job
    const unsigned* seg[10]; int nseg;
    const float* sx[5]; int sxrow[5]; int nsx;
    const unsigned short* Wh[2]; const unsigned short* Wl[2];
    const float* WO[2]; const float* bias[2];
    const float* h; unsigned* GP; float* Z;
    float* PR;                   // mode 1 output: gate-stacked preacts
    int mode;                    // 0 = full, 1 = MFMA-only preact
};

struct NJob {                    // n-gate job
    const unsigned* seg[10]; int nseg; int ksplit;
    const float* sx[5]; int sxrow[5]; int nsx;
    const unsigned short* Wh; const unsigned short* Wl;
    const float* WO; const float* bias;
    const float* Zb; const float* hin; float* hout; unsigned* hPout;
    int doProj; const float* Wp; const float* bp; float* out; float* di; int t;
};

struct F0 {                      // decoder finish0 (efficient v2)
    const float* M[4];           // Wf, W2f, Wb, W2b (fp32)
    const float* di;
    const float* PR;             // [2][NB*64] MFMA preacts from rz0big
    const float* WO[2]; const float* bias[2];  // Wr0/Wz0 fp32, br0/bz0
    const float* h0;
    unsigned* GP0; float* Z0; float* HXS;      // HXS[m*NB + row]
};

// ---------------------------------------------------------------------------
// Setup kernels
// ---------------------------------------------------------------------------
__global__ void sumfill_kernel(const float* __restrict__ A, float* __restrict__ Wf,
                               float* __restrict__ Wb) {
    int i = blockIdx.x;
    int t = threadIdx.x;
    __shared__ float s1[256], s2[256];
    float a = A[i * 512 + t] + A[i * 512 + t + 256];
    float b = A[t * 512 + i] + A[(t + 256) * 512 + i];
    s1[t] = a; s2[t] = b;
    __syncthreads();
    for (int off = 128; off > 0; off >>= 1) {
        if (t < off) { s1[t] += s1[t + off]; s2[t] += s2[t + off]; }
        __syncthreads();
    }
    float irs = 1.0f / (s1[0] + EPSV);
    float ics = 1.0f / (s2[0] + EPSV);
    for (int j = t; j < 512; j += 256) {
        Wf[i * 512 + j] = A[i * 512 + j] * irs;
        Wb[i * 512 + j] = A[j * 512 + i] * ics;
    }
}

__global__ void xenc_kernel(const float* __restrict__ x, float* __restrict__ xenc) {
    int idx = blockIdx.x * 256 + threadIdx.x;
    if (idx >= T_IN * NB) return;
    int j = idx & 511;
    int b = (idx >> 9) & 15;
    int t = idx >> 13;
    xenc[t * NB + j * 16 + b] = x[(b * T_IN + t) * 512 + j];
}

// fp32 GEMM for the setup-only W^2 = W @ W build. 64x64 tile, 4x4 micro.
__global__ __launch_bounds__(256) void ghop_kernel(HopA a) {
    int z = blockIdx.z;
    const float* Wm = a.M[z];
    const float* X = Wm;
    float* Y = a.dst0[z];
    int col0 = blockIdx.x * 64;
    int row0 = blockIdx.y * 64;
    int tid = threadIdx.x;
    int tx = tid & 15, ty = tid >> 4;
    int kkA = tid & 15, rrA = tid >> 4;
    int ccB = tid & 63, kkB = tid >> 6;

    __shared__ float As[16][68], Bs[16][68];
    float acc[4][4] = {};

    const float* wp = Wm + (row0 + rrA) * 512 + kkA;
    const float* xp = X + (size_t)(col0 + ccB) + (size_t)kkB * 512;

    float ra[4], rb[4];
#pragma unroll
    for (int p = 0; p < 4; ++p) ra[p] = wp[p * 16 * 512];
#pragma unroll
    for (int p = 0; p < 4; ++p) rb[p] = xp[(size_t)(p * 4) * 512];

    for (int k0 = 0; k0 < 512; k0 += 16) {
#pragma unroll
        for (int p = 0; p < 4; ++p) As[kkA][rrA + p * 16] = ra[p];
#pragma unroll
        for (int p = 0; p < 4; ++p) Bs[kkB + p * 4][ccB] = rb[p];
        __syncthreads();
        if (k0 + 16 < 512) {
            int kn = k0 + 16;
#pragma unroll
            for (int p = 0; p < 4; ++p) ra[p] = wp[p * 16 * 512 + kn];
#pragma unroll
            for (int p = 0; p < 4; ++p) rb[p] = xp[(size_t)(kn + p * 4) * 512];
        }
#pragma unroll
        for (int k = 0; k < 16; ++k) {
            const float4 a4 = *(const float4*)&As[k][ty * 4];
            const float4 b4 = *(const float4*)&Bs[k][tx * 4];
            float av[4] = { a4.x, a4.y, a4.z, a4.w };
            float bv[4] = { b4.x, b4.y, b4.z, b4.w };
#pragma unroll
            for (int i = 0; i < 4; ++i)
#pragma unroll
                for (int j = 0; j < 4; ++j)
                    acc[i][j] = fmaf(av[i], bv[j], acc[i][j]);
        }
        __syncthreads();
    }

    int colw = col0 + tx * 4;
#pragma unroll
    for (int i = 0; i < 4; ++i) {
        int row = row0 + ty * 4 + i;
        *(float4*)&Y[(size_t)row * 512 + colw] =
            make_float4(acc[i][0], acc[i][1], acc[i][2], acc[i][3]);
    }
}

// Pack W (512x512 fp32) into A-fragment-contiguous bf16 hi/lo (for hops)
__global__ void wpack_kernel(WPack a) {
    int z = blockIdx.y;
    int idx = blockIdx.x * 256 + threadIdx.x;   // 0..262143
    int m = idx >> 9, k = idx & 511;
    float x = a.w[z][idx];
    unsigned short h = f2bf(x);
    unsigned short l = f2bf(x - bf2f(h));
    int p = (((m >> 4) * 64 + (k >> 3)) * 16 + (m & 15)) * 8 + (k & 7);
    a.hi[z][p] = h;
    a.lo[z][p] = l;
}

// Pack all 6 lin weight matrices into B-fragment order over len-64 segments.
__global__ void lpack_all_kernel(LPackAll p) {
    int g = blockIdx.y;
    int nseg = (g < 3) ? 5 : 10;
    int idx = blockIdx.x * 256 + threadIdx.x;
    if (idx >= nseg * 4096) return;
    int j = idx & 7, ln = (idx >> 3) & 15, ntl = (idx >> 7) & 3, O = idx >> 9;
    int s = O >> 3, o8 = O & 7;
    int base = (g < 3) ? (65 * s + 1) : (64 * s);
    int row = base + o8 * 8 + j;
    int col = ntl * 16 + ln;
    float v = p.W[g][(size_t)row * 64 + col];
    unsigned short h = f2bf(v);
    p.hi[g][idx] = h;
    p.lo[g][idx] = f2bf(v - bf2f(h));
}

// ---------------------------------------------------------------------------
// MFMA hop GEMM v2: LDS-free, z-paired.  Block = 32m x 64n, 4 waves
// (2 wm x 2 wn); each wave computes 16m x 32n for BOTH z of the pair,
// loading B fragments directly from P-format global (coalesced dwords,
// hi+lo in one load) and sharing them across the two z.  No barriers.
// ---------------------------------------------------------------------------
__global__ __launch_bounds__(256) void hop2_mfma(HopM a) {
    int zp = blockIdx.z;               // z pair {2zp, 2zp+1}
    int nt = blockIdx.x;
    const unsigned* X; unsigned* Y0; unsigned* Y1; int c0;
    if (nt < a.tiles0) {
        X = a.src0; Y0 = a.dst0[2 * zp]; Y1 = a.dst0[2 * zp + 1]; c0 = nt * 64;
    } else {
        X = a.src1; Y0 = a.dst1[2 * zp]; Y1 = a.dst1[2 * zp + 1];
        c0 = (nt - a.tiles0) * 64;
    }
    const unsigned short* Ahi0 = a.Ahi[2 * zp];
    const unsigned short* Alo0 = a.Alo[2 * zp];
    const unsigned short* Ahi1 = a.Ahi[2 * zp + 1];
    const unsigned short* Alo1 = a.Alo[2 * zp + 1];
    int bm = blockIdx.y * 32;

    int tid = threadIdx.x;
    int lane = tid & 63, w = tid >> 6;
    int wm = (w & 1) * 16, wn = (w >> 1) * 32;
    int ln = lane & 15, quad = lane >> 4;
    int mtb = (bm + wm) >> 4;

    floatx4 acc[2][2];                 // [zz][ci]
#pragma unroll
    for (int zz = 0; zz < 2; ++zz)
#pragma unroll
        for (int ci = 0; ci < 2; ++ci) acc[zz][ci] = (floatx4)0.0f;

    const unsigned* xc = X + c0 + wn + ln;

#pragma unroll
    for (int it = 0; it < 16; ++it) {
        int kob = it * 4 + quad;
        const unsigned* base = xc + (size_t)(kob * 8) * 1024;
        unsigned u[2][8];
#pragma unroll
        for (int ci = 0; ci < 2; ++ci)
#pragma unroll
            for (int j = 0; j < 8; ++j)
                u[ci][j] = base[ci * 16 + (size_t)j * 1024];
        size_t aoff = ((size_t)(mtb * 64 + kob) * 16 + ln) * 8;
        short8 A0h = *(const short8*)(Ahi0 + aoff);
        short8 A0l = *(const short8*)(Alo0 + aoff);
        short8 A1h = *(const short8*)(Ahi1 + aoff);
        short8 A1l = *(const short8*)(Alo1 + aoff);
#pragma unroll
        for (int ci = 0; ci < 2; ++ci) {
            short8 bh, bl;
#pragma unroll
            for (int j = 0; j < 8; ++j) {
                bh[j] = (short)(u[ci][j] & 0xffffu);
                bl[j] = (short)(u[ci][j] >> 16);
            }
            acc[0][ci] = __builtin_amdgcn_mfma_f32_16x16x32_bf16(A0h, bh, acc[0][ci], 0, 0, 0);
            acc[0][ci] = __builtin_amdgcn_mfma_f32_16x16x32_bf16(A0h, bl, acc[0][ci], 0, 0, 0);
            acc[0][ci] = __builtin_amdgcn_mfma_f32_16x16x32_bf16(A0l, bh, acc[0][ci], 0, 0, 0);
            acc[1][ci] = __builtin_amdgcn_mfma_f32_16x16x32_bf16(A1h, bh, acc[1][ci], 0, 0, 0);
            acc[1][ci] = __builtin_amdgcn_mfma_f32_16x16x32_bf16(A1h, bl, acc[1][ci], 0, 0, 0);
            acc[1][ci] = __builtin_amdgcn_mfma_f32_16x16x32_bf16(A1l, bh, acc[1][ci], 0, 0, 0);
        }
    }

#pragma unroll
    for (int zz = 0; zz < 2; ++zz) {
        unsigned* Y = zz ? Y1 : Y0;
#pragma unroll
        for (int ci = 0; ci < 2; ++ci) {
            int mrow = bm + wm + quad * 4;
            int col = c0 + wn + ci * 16 + ln;
#pragma unroll
            for (int r = 0; r < 4; ++r)
                Y[(size_t)(mrow + r) * 1024 + col] = packbf(acc[zz][ci][r]);
        }
    }
}

// ---------------------------------------------------------------------------
// MFMA x-hop (setup + decoder): fp32 in/out. Block 64m x 64n (LDS version).
// ---------------------------------------------------------------------------
__global__ __launch_bounds__(256) void xhop_mfma(XHopM a) {
    int z = blockIdx.z;
    int c0 = blockIdx.x * 64;
    const unsigned short* Ahi = a.Ahi[z];
    const unsigned short* Alo = a.Alo[z];
    int bm = blockIdx.y * 64;

    __shared__ unsigned short Bhi_s[2][64][40];
    __shared__ unsigned short Blo_s[2][64][40];

    int tid = threadIdx.x;
    int lane = tid & 63, w = tid >> 6;
    int wm = (w & 1) * 32, wn = (w >> 1) * 32;
    int ln = lane & 15, quad = lane >> 4;
    int sc = tid & 63, skh = tid >> 6;

    floatx4 acc[2][2];
#pragma unroll
    for (int mi = 0; mi < 2; ++mi)
#pragma unroll
        for (int ci = 0; ci < 2; ++ci) acc[mi][ci] = (floatx4)0.0f;

    int colS = c0 + sc;
    bool ok = colS < a.ncols;
    const float* xb = a.X + (size_t)(colS >> 4) * NB + (colS & 15);
    int mtb = (bm + wm) >> 4;

    float xv[8];
#pragma unroll
    for (int j = 0; j < 8; ++j)
        xv[j] = ok ? xb[(size_t)(skh * 8 + j) * 16] : 0.0f;
    {
        short8 h8, l8;
#pragma unroll
        for (int j = 0; j < 8; ++j) { short h, l; split2(xv[j], h, l); h8[j] = h; l8[j] = l; }
        *(short8*)&Bhi_s[0][sc][skh * 8] = h8;
        *(short8*)&Blo_s[0][sc][skh * 8] = l8;
    }
#pragma unroll
    for (int j = 0; j < 8; ++j)
        xv[j] = ok ? xb[(size_t)(32 + skh * 8 + j) * 16] : 0.0f;

    for (int it = 0; it < 16; ++it) {
        __syncthreads();
        int cur = it & 1;
        if (it + 1 < 16) {
            short8 h8, l8;
#pragma unroll
            for (int j = 0; j < 8; ++j) { short h, l; split2(xv[j], h, l); h8[j] = h; l8[j] = l; }
            *(short8*)&Bhi_s[cur ^ 1][sc][skh * 8] = h8;
            *(short8*)&Blo_s[cur ^ 1][sc][skh * 8] = l8;
        }
        if (it + 2 < 16) {
            int kn = (it + 2) * 32;
#pragma unroll
            for (int j = 0; j < 8; ++j)
                xv[j] = ok ? xb[(size_t)(kn + skh * 8 + j) * 16] : 0.0f;
        }
        short8 bh[2], bl[2];
#pragma unroll
        for (int ci = 0; ci < 2; ++ci) {
            bh[ci] = *(const short8*)&Bhi_s[cur][wn + ci * 16 + ln][quad * 8];
            bl[ci] = *(const short8*)&Blo_s[cur][wn + ci * 16 + ln][quad * 8];
        }
        int kob = it * 4 + quad;
#pragma unroll
        for (int mi = 0; mi < 2; ++mi) {
            size_t aoff = ((size_t)((mtb + mi) * 64 + kob) * 16 + ln) * 8;
            short8 Ah = *(const short8*)(Ahi + aoff);
            short8 Al = *(const short8*)(Alo + aoff);
#pragma unroll
            for (int ci = 0; ci < 2; ++ci) {
                acc[mi][ci] = __builtin_amdgcn_mfma_f32_16x16x32_bf16(Ah, bh[ci], acc[mi][ci], 0, 0, 0);
                acc[mi][ci] = __builtin_amdgcn_mfma_f32_16x16x32_bf16(Ah, bl[ci], acc[mi][ci], 0, 0, 0);
                acc[mi][ci] = __builtin_amdgcn_mfma_f32_16x16x32_bf16(Al, bh[ci], acc[mi][ci], 0, 0, 0);
            }
        }
    }

#pragma unroll
    for (int mi = 0; mi < 2; ++mi) {
#pragma unroll
        for (int ci = 0; ci < 2; ++ci) {
            int col = c0 + wn + ci * 16 + ln;
            if (col < a.ncols) {
                int mrow = bm + wm + mi * 16 + quad * 4;
                float* yb = a.Y + (size_t)((col >> 4) * 4 + z) * NB + (col & 15);
#pragma unroll
                for (int r = 0; r < 4; ++r)
                    yb[(size_t)(mrow + r) * 16] = acc[mi][ci][r];
            }
        }
    }
}

// ---------------------------------------------------------------------------
// MFMA lin core (ci-split, seg-range): wave computes 16 rows x 32 cols.
// ---------------------------------------------------------------------------
__device__ __forceinline__ void lin_core2(const unsigned* const* segs, int nseg, int s0,
        const unsigned short* __restrict__ Bh, const unsigned short* __restrict__ Bl,
        int row0, int ln, int quad, int cihalf, floatx4 acc[2]) {
    for (int s = 0; s < nseg; ++s) {
        const unsigned* ap = segs[s] + (size_t)(row0 + ln) * 64 + quad * 8;
#pragma unroll
        for (int hh = 0; hh < 2; ++hh) {
            unsigned u[8];
            *(uint4*)&u[0] = *(const uint4*)(ap + hh * 32);
            *(uint4*)&u[4] = *(const uint4*)(ap + hh * 32 + 4);
            short8 Ah, Al;
#pragma unroll
            for (int j = 0; j < 8; ++j) {
                Ah[j] = (short)(u[j] & 0xffffu);
                Al[j] = (short)(u[j] >> 16);
            }
            int O = (s0 + s) * 8 + hh * 4 + quad;
#pragma unroll
            for (int ci = 0; ci < 2; ++ci) {
                int c_abs = cihalf * 2 + ci;
                size_t boff = ((size_t)(O * 4 + c_abs) * 16 + ln) * 8;
                short8 B1 = *(const short8*)(Bh + boff);
                short8 B2 = *(const short8*)(Bl + boff);
                acc[ci] = __builtin_amdgcn_mfma_f32_16x16x32_bf16(Ah, B1, acc[ci], 0, 0, 0);
                acc[ci] = __builtin_amdgcn_mfma_f32_16x16x32_bf16(Al, B1, acc[ci], 0, 0, 0);
                acc[ci] = __builtin_amdgcn_mfma_f32_16x16x32_bf16(Ah, B2, acc[ci], 0, 0, 0);
            }
        }
    }
}

__device__ __forceinline__ void lin_scalar2p(const float* const* sx, const int* sxrow,
        int nsx, const float* __restrict__ WO,
        int row0, int ln, int quad, int cihalf, floatx4 acc[2]) {
    for (int t = 0; t < nsx; ++t) {
        const float* wr = WO + (size_t)sxrow[t] * 64;
        const float* sv = sx[t] + row0 + quad * 4;
#pragma unroll
        for (int rr = 0; rr < 4; ++rr) {
            float v = sv[rr];
#pragma unroll
            for (int ci = 0; ci < 2; ++ci)
                acc[ci][rr] = fmaf(v, wr[(cihalf * 2 + ci) * 16 + ln], acc[ci][rr]);
        }
    }
}

// rz body — inlined per branch so the kernarg struct is accessed directly
// (NO runtime-selected reference: that forced both structs to scratch, R10).
__device__ __forceinline__ void rz_body(const LinJob& J, int bx) {
    int w = threadIdx.x >> 6, lane = threadIdx.x & 63;
    int ln = lane & 15, quad = lane >> 4;
    int row0 = bx * 64 + w * 16;
    int gate = blockIdx.y;
    int cihalf = blockIdx.z;
    floatx4 acc[2];
    acc[0] = (floatx4)0.0f; acc[1] = (floatx4)0.0f;
    lin_core2(J.seg, J.nseg, 0, J.Wh[gate], J.Wl[gate], row0, ln, quad, cihalf, acc);
    if (J.nsx) lin_scalar2p(J.sx, J.sxrow, J.nsx, J.WO[gate], row0, ln, quad, cihalf, acc);
    if (J.mode == 0) {
        const float* bias = J.bias[gate];
#pragma unroll
        for (int ci = 0; ci < 2; ++ci) {
            int col = (cihalf * 2 + ci) * 16 + ln;
            float bv = bias[col];
#pragma unroll
            for (int rr = 0; rr < 4; ++rr) {
                int row = row0 + quad * 4 + rr;
                size_t idx = (size_t)row * 64 + col;
                float sg = sigmoid_fast(acc[ci][rr] + bv);
                if (gate == 0) J.GP[idx] = packbf(sg * J.h[idx]);
                else J.Z[idx] = sg;
            }
        }
    } else {
        float* PRg = J.PR + (size_t)gate * ((size_t)NB * 64);
#pragma unroll
        for (int ci = 0; ci < 2; ++ci) {
            int col = (cihalf * 2 + ci) * 16 + ln;
#pragma unroll
            for (int rr = 0; rr < 4; ++rr) {
                int row = row0 + quad * 4 + rr;
                PRg[(size_t)row * 64 + col] = acc[ci][rr];
            }
        }
    }
}

// r/z gates, up to two jobs per launch: grid (x, 2 gates, 2 cihalf).
__global__ __launch_bounds__(256) void lin_rz2(LinJob j0, LinJob j1, int xsplit) {
    if ((int)blockIdx.x >= xsplit) rz_body(j1, (int)blockIdx.x - xsplit);
    else                           rz_body(j0, (int)blockIdx.x);
}

// n-gate body — same inlining rule as rz_body.
__device__ __forceinline__ void n_body(const NJob& J, int bx) {
    int w = threadIdx.x >> 6, lane = threadIdx.x & 63;
    int ln = lane & 15, quad = lane >> 4;
    int kh = w & 1, cihalf = w >> 1;
    int row0 = bx * 16;
    __shared__ float part[2][2][16][17];
    __shared__ float pr[2][16];
    floatx4 acc[2];
    acc[0] = (floatx4)0.0f; acc[1] = (floatx4)0.0f;
    if (kh == 0) {
        lin_core2(J.seg, J.ksplit, 0, J.Wh, J.Wl, row0, ln, quad, cihalf, acc);
    } else {
        lin_core2(J.seg + J.ksplit, J.nseg - J.ksplit, J.ksplit, J.Wh, J.Wl,
                  row0, ln, quad, cihalf, acc);
        if (J.nsx) lin_scalar2p(J.sx, J.sxrow, J.nsx, J.WO, row0, ln, quad, cihalf, acc);
#pragma unroll
        for (int ci = 0; ci < 2; ++ci)
#pragma unroll
            for (int rr = 0; rr < 4; ++rr)
                part[cihalf][ci][quad * 4 + rr][ln] = acc[ci][rr];
    }
    __syncthreads();
    float p[4] = {0.0f, 0.0f, 0.0f, 0.0f};
    if (kh == 0) {
#pragma unroll
        for (int ci = 0; ci < 2; ++ci) {
            int col = (cihalf * 2 + ci) * 16 + ln;
            float bv = J.bias[col];
            float wpv = J.doProj ? J.Wp[col] : 0.0f;
#pragma unroll
            for (int rr = 0; rr < 4; ++rr) {
                int row = row0 + quad * 4 + rr;
                size_t idx = (size_t)row * 64 + col;
                float pre = acc[ci][rr] + part[cihalf][ci][quad * 4 + rr][ln] + bv;
                float nn = tanh_fast(pre);
                float z = J.Zb[idx];
                float hv = J.hin[idx];
                float o = (1.0f - z) * hv + z * nn;
                J.hout[idx] = o;
                J.hPout[idx] = packbf(o);
                p[rr] = fmaf(o, wpv, p[rr]);
            }
        }
        if (J.doProj) {
#pragma unroll
            for (int rr = 0; rr < 4; ++rr) {
                p[rr] += __shfl_xor(p[rr], 1, 64);
                p[rr] += __shfl_xor(p[rr], 2, 64);
                p[rr] += __shfl_xor(p[rr], 4, 64);
                p[rr] += __shfl_xor(p[rr], 8, 64);
            }
            if (ln == 0) {
#pragma unroll
                for (int rr = 0; rr < 4; ++rr)
                    pr[cihalf][quad * 4 + rr] = p[rr];
            }
        }
    }
    __syncthreads();
    if (J.doProj && kh == 0 && cihalf == 0 && ln == 0) {
        float bpv = J.bp[0];
#pragma unroll
        for (int rr = 0; rr < 4; ++rr) {
            int qr = quad * 4 + rr;
            int row = row0 + qr;
            float y = pr[0][qr] + pr[1][qr] + bpv;
            int n = row >> 4, b = row & 15;
            J.out[(b * T_OUT + J.t) * 512 + n] = y;
            J.di[row] = y;
        }
    }
}

// n gate + GRU update, up to two jobs per launch.
__global__ __launch_bounds__(256) void lin_n2(NJob j0, NJob j1, int xsplit) {
    if ((int)blockIdx.x >= xsplit) n_body(j1, (int)blockIdx.x - xsplit);
    else                           n_body(j0, (int)blockIdx.x);
}

// ---------------------------------------------------------------------------
// Decoder finish0 v2: 512 blocks (one node each).  Phase 1: 4 di-hops per
// node (64 dots, 4-way split-K, 4 accumulators).  Phase 2: rank-5 scalar
// update on rz0big preacts + sigmoid -> GP0/Z0.  Single by-value struct.
// ---------------------------------------------------------------------------
__global__ __launch_bounds__(256) void finish0_kernel(F0 a) {
    int n = blockIdx.x;                 // node; rows n*16 .. n*16+15
    int tid = threadIdx.x;
    __shared__ float hopS[4][16];
    __shared__ float sdi[16];

    // phase 1: hop_m[b] = sum_k M[m][n][k] * di[k*16+b]
    int g = tid >> 2;                   // 0..63 : m*16+b
    int sub = tid & 3;                  // k-quarter
    int m = g >> 4, b = g & 15;
    const float* wrow = a.M[m] + (size_t)n * 512 + sub * 128;
    const float* dv = a.di + (size_t)(sub * 128) * 16 + b;
    float s0 = 0.0f, s1 = 0.0f, s2 = 0.0f, s3 = 0.0f;
#pragma unroll 8
    for (int k = 0; k < 128; k += 4) {
        float4 w4 = *(const float4*)&wrow[k];
        s0 = fmaf(w4.x, dv[(k + 0) * 16], s0);
        s1 = fmaf(w4.y, dv[(k + 1) * 16], s1);
        s2 = fmaf(w4.z, dv[(k + 2) * 16], s2);
        s3 = fmaf(w4.w, dv[(k + 3) * 16], s3);
    }
    float sv = (s0 + s1) + (s2 + s3);
    sv += __shfl_xor(sv, 1, 64);
    sv += __shfl_xor(sv, 2, 64);
    if (sub == 0) {
        hopS[m][b] = sv;
        a.HXS[(size_t)m * NB + n * 16 + b] = sv;
    }
    if (tid < 16) sdi[tid] = a.di[n * 16 + tid];
    __syncthreads();

    // phase 2: 2 gates x 16 rows x 64 cols
    int gate = tid >> 7, col = tid & 63, rh = (tid >> 6) & 1;
    const float* WOg = a.WO[gate];
    float w0c = WOg[col];
    float wmc[4];
#pragma unroll
    for (int mm = 0; mm < 4; ++mm)
        wmc[mm] = WOg[(size_t)(65 * (mm + 1)) * 64 + col];
    float bv = a.bias[gate][col];
    const float* PRg = a.PR + (size_t)gate * ((size_t)NB * 64);
#pragma unroll
    for (int rr = 0; rr < 8; ++rr) {
        int bl = rh * 8 + rr;
        int row = n * 16 + bl;
        size_t idx = (size_t)row * 64 + col;
        float pre = PRg[idx] + bv + sdi[bl] * w0c;
#pragma unroll
        for (int mm = 0; mm < 4; ++mm)
            pre = fmaf(hopS[mm][bl], wmc[mm], pre);
        float sg = sigmoid_fast(pre);
        if (gate == 0) a.GP0[idx] = packbf(sg * a.h0[idx]);
        else a.Z0[idx] = sg;
    }
}

// ---------------------------------------------------------------------------
extern "C" void kernel_launch(void* const* d_in, const int* in_sizes, int n_in,
                              void* d_out, int out_size, void* d_ws, size_t ws_size,
                              hipStream_t stream) {
    (void)in_sizes; (void)n_in; (void)out_size; (void)ws_size;
    const float* x   = (const float*)d_in[0];
    const float* A   = (const float*)d_in[1];
    const float* Wr0 = (const float*)d_in[2];  const float* br0 = (const float*)d_in[3];
    const float* Wz0 = (const float*)d_in[4];  const float* bz0 = (const float*)d_in[5];
    const float* Wn0 = (const float*)d_in[6];  const float* bn0 = (const float*)d_in[7];
    const float* Wr1 = (const float*)d_in[8];  const float* br1 = (const float*)d_in[9];
    const float* Wz1 = (const float*)d_in[10]; const float* bz1 = (const float*)d_in[11];
    const float* Wn1 = (const float*)d_in[12]; const float* bn1 = (const float*)d_in[13];
    const float* Wp  = (const float*)d_in[14]; const float* bp  = (const float*)d_in[15];
    float* out = (float*)d_out;

    float* ws = (float*)d_ws;
    size_t off = 0;
    auto alloc = [&](size_t nf) { float* p = ws + off; off += nf; return p; };
    const size_t NB64 = (size_t)NB * 64;
    float* Wf  = alloc(262144); float* Wb  = alloc(262144);
    float* W2f = alloc(262144); float* W2b = alloc(262144);
    float* xenc = alloc((size_t)T_IN * NB);
    unsigned short* Whi[4]; unsigned short* Wlo[4];
    for (int m = 0; m < 4; ++m) Whi[m] = (unsigned short*)alloc(131072);
    for (int m = 0; m < 4; ++m) Wlo[m] = (unsigned short*)alloc(131072);
    // contiguous zero-init group: h0x[1], h0Px[1], h1, h1P, HAall(4), HBall(4)
    float* zbase = alloc(12 * NB64);
    float* h0x[2]; unsigned* h0Px[2];
    h0x[1]  = zbase;
    h0Px[1] = (unsigned*)(zbase + NB64);
    float* h1 = zbase + 2 * NB64;
    unsigned* h1P = (unsigned*)(zbase + 3 * NB64);
    unsigned* HAall = (unsigned*)(zbase + 4 * NB64);
    unsigned* HBall = (unsigned*)(zbase + 8 * NB64);
    unsigned* HA[4]; unsigned* HB[4]; unsigned* HG0[4]; unsigned* HG1[4];
    for (int m = 0; m < 4; ++m) HA[m] = HAall + m * NB64;
    for (int m = 0; m < 4; ++m) HB[m] = HBall + m * NB64;
    for (int m = 0; m < 4; ++m) HG0[m] = (unsigned*)alloc(NB64);
    for (int m = 0; m < 4; ++m) HG1[m] = (unsigned*)alloc(NB64);
    unsigned* GP0 = (unsigned*)alloc(NB64);
    unsigned* GP1 = (unsigned*)alloc(NB64);
    float* Z0 = alloc(NB64);
    float* Z1 = alloc(NB64);
    h0x[0]  = alloc(NB64);
    h0Px[0] = (unsigned*)alloc(NB64);
    float* PR0 = alloc(2 * NB64);
    float* XHE = alloc((size_t)T_IN * 4 * NB);
    float* HXSdec = alloc(4 * NB);
    float* di = alloc(NB);
    unsigned short* LWh[6]; unsigned short* LWl[6];
    for (int g = 0; g < 3; ++g) { LWh[g] = (unsigned short*)alloc(10240); LWl[g] = (unsigned short*)alloc(10240); }
    for (int g = 3; g < 6; ++g) { LWh[g] = (unsigned short*)alloc(20480); LWl[g] = (unsigned short*)alloc(20480); }

    hipMemsetAsync(zbase, 0, 12 * NB64 * 4, stream);

    xenc_kernel<<<dim3((T_IN * NB) / 256), 256, 0, stream>>>(x, xenc);
    sumfill_kernel<<<dim3(512), 256, 0, stream>>>(A, Wf, Wb);
    {
        HopA w2 = {};
        w2.M[0] = Wf; w2.M[1] = Wb;
        w2.dst0[0] = W2f; w2.dst0[1] = W2b;
        ghop_kernel<<<dim3(8, 8, 2), 256, 0, stream>>>(w2);
    }
    {
        WPack p;
        p.w[0] = Wf; p.w[1] = W2f; p.w[2] = Wb; p.w[3] = W2b;
        for (int m = 0; m < 4; ++m) { p.hi[m] = Whi[m]; p.lo[m] = Wlo[m]; }
        wpack_kernel<<<dim3(1024, 4), 256, 0, stream>>>(p);
    }
    {
        LPackAll p;
        const float* WG[6] = { Wr0, Wz0, Wn0, Wr1, Wz1, Wn1 };
        for (int g = 0; g < 6; ++g) { p.W[g] = WG[g]; p.hi[g] = LWh[g]; p.lo[g] = LWl[g]; }
        lpack_all_kernel<<<dim3(160, 6), 256, 0, stream>>>(p);
    }
    {
        XHopM xa = {};
        for (int m = 0; m < 4; ++m) { xa.Ahi[m] = Whi[m]; xa.Alo[m] = Wlo[m]; }
        xa.X = xenc; xa.Y = XHE; xa.ncols = 192;
        xhop_mfma<<<dim3(3, 8, 4), 256, 0, stream>>>(xa);
    }

    // hop launchers (LDS-free z-paired kernel).
    auto hopSingle = [&](const unsigned* s0, unsigned* const* d0) {
        HopM a = {};
        for (int m = 0; m < 4; ++m) { a.Ahi[m] = Whi[m]; a.Alo[m] = Wlo[m]; }
        a.src0 = s0; a.tiles0 = 16;
        for (int m = 0; m < 4; ++m) a.dst0[m] = d0[m];
        hop2_mfma<<<dim3(16, 16, 2), 256, 0, stream>>>(a);
    };
    auto hopDual = [&](const unsigned* s0, unsigned* const* d0,
                       const unsigned* s1, unsigned* const* d1) {
        HopM a = {};
        for (int m = 0; m < 4; ++m) { a.Ahi[m] = Whi[m]; a.Alo[m] = Wlo[m]; }
        a.src0 = s0; a.tiles0 = 16;
        for (int m = 0; m < 4; ++m) a.dst0[m] = d0[m];
        a.src1 = s1;
        for (int m = 0; m < 4; ++m) a.dst1[m] = d1[m];
        hop2_mfma<<<dim3(32, 16, 2), 256, 0, stream>>>(a);
    };

    auto mkRZ1 = [&](int t) {
        LinJob J = {};
        J.seg[0] = h0Px[t & 1]; J.seg[1] = h1P;
        for (int m = 0; m < 4; ++m) { J.seg[2 + 2 * m] = HA[m]; J.seg[3 + 2 * m] = HB[m]; }
        J.nseg = 10; J.nsx = 0;
        J.Wh[0] = LWh[3]; J.Wl[0] = LWl[3]; J.Wh[1] = LWh[4]; J.Wl[1] = LWl[4];
        J.WO[0] = Wr1; J.WO[1] = Wz1; J.bias[0] = br1; J.bias[1] = bz1;
        J.h = h1; J.GP = GP1; J.Z = Z1; J.mode = 0;
        return J;
    };
    auto mkRZ0 = [&](int tn, const float* xc, const float* hx, int mode) {
        LinJob J = {};
        J.seg[0] = h0Px[(tn - 1) & 1];
        for (int m = 0; m < 4; ++m) J.seg[1 + m] = HA[m];
        J.nseg = 5;
        if (mode == 0) {
            J.nsx = 5;
            J.sx[0] = xc; J.sxrow[0] = 0;
            for (int m = 0; m < 4; ++m) { J.sx[1 + m] = hx + (size_t)m * NB; J.sxrow[1 + m] = 65 * (m + 1); }
        }
        J.Wh[0] = LWh[0]; J.Wl[0] = LWl[0]; J.Wh[1] = LWh[1]; J.Wl[1] = LWl[1];
        J.WO[0] = Wr0; J.WO[1] = Wz0; J.bias[0] = br0; J.bias[1] = bz0;
        J.h = h0x[(tn - 1) & 1]; J.GP = GP0; J.Z = Z0; J.PR = PR0; J.mode = mode;
        return J;
    };
    auto mkN1 = [&](int t) {
        NJob J = {};
        J.seg[0] = h0Px[t & 1]; J.seg[1] = GP1;
        for (int m = 0; m < 4; ++m) { J.seg[2 + 2 * m] = HA[m]; J.seg[3 + 2 * m] = HG1[m]; }
        J.nseg = 10; J.ksplit = 5; J.nsx = 0;
        J.Wh = LWh[5]; J.Wl = LWl[5]; J.WO = Wn1; J.bias = bn1;
        J.Zb = Z1; J.hin = h1; J.hout = h1; J.hPout = h1P;
        J.doProj = (t >= T_IN); J.Wp = Wp; J.bp = bp; J.out = out; J.di = di; J.t = t - T_IN;
        return J;
    };
    auto mkN0 = [&](int tn, const float* xc, const float* hx) {
        NJob J = {};
        J.seg[0] = GP0;
        for (int m = 0; m < 4; ++m) J.seg[1 + m] = HG0[m];
        J.nseg = 5; J.ksplit = 3;
        J.nsx = 5;
        J.sx[0] = xc; J.sxrow[0] = 0;
        for (int m = 0; m < 4; ++m) { J.sx[1 + m] = hx + (size_t)m * NB; J.sxrow[1 + m] = 65 * (m + 1); }
        J.Wh = LWh[2]; J.Wl = LWl[2]; J.WO = Wn0; J.bias = bn0;
        J.Zb = Z0; J.hin = h0x[(tn - 1) & 1]; J.hout = h0x[tn & 1]; J.hPout = h0Px[tn & 1];
        J.doProj = 0;
        return J;
    };

    auto rz2one = [&](LinJob a) { lin_rz2<<<dim3(128, 2, 2), 256, 0, stream>>>(a, a, 128); };
    auto rz2two = [&](LinJob a, LinJob b) { lin_rz2<<<dim3(256, 2, 2), 256, 0, stream>>>(a, b, 128); };
    auto n2one = [&](NJob a) { lin_n2<<<dim3(512), 256, 0, stream>>>(a, a, 512); };
    auto n2two = [&](NJob a, NJob b) { lin_n2<<<dim3(1024), 256, 0, stream>>>(a, b, 512); };

    // ---- prologue: cell0 of step 0 -----------------------------------------
    rz2one(mkRZ0(0, xenc, XHE, 0));
    hopSingle(GP0, HG0);
    n2one(mkN0(0, xenc, XHE));
    hopSingle(h0Px[0], HA);

    // ---- main loop: iter t = (cell1 of t) + (cell0 of t+1) -----------------
    for (int t = 0; t < T_IN + T_OUT; ++t) {
        int tn = t + 1;
        bool last = (t == T_IN + T_OUT - 1);
        bool decFeed = (tn >= T_IN + 1);   // cell0(tn) needs di from n1(t)
        if (!last && !decFeed) {
            // Encoder-style paired iteration (x for cell0(tn) known upfront)
            int ts = (tn < T_IN) ? tn : (T_IN - 1);
            const float* xc = xenc + (size_t)ts * NB;
            const float* hx = XHE + (size_t)ts * 4 * NB;
            rz2two(mkRZ1(t), mkRZ0(tn, xc, hx, 0));
            hopDual(GP1, HG1, GP0, HG0);
            n2two(mkN1(t), mkN0(tn, xc, hx));
            hopDual(h0Px[tn & 1], HA, h1P, HB);
        } else if (!last) {
            // Decoder iteration: rz0's MFMA part is di-independent -> pair it.
            rz2two(mkRZ1(t), mkRZ0(tn, nullptr, nullptr, 1));
            hopSingle(GP1, HG1);
            n2one(mkN1(t));                       // writes di, out[t-T_IN]
            {
                F0 f = {};
                f.M[0] = Wf; f.M[1] = W2f; f.M[2] = Wb; f.M[3] = W2b;
                f.di = di; f.PR = PR0;
                f.WO[0] = Wr0; f.WO[1] = Wz0; f.bias[0] = br0; f.bias[1] = bz0;
                f.h0 = h0x[t & 1];
                f.GP0 = GP0; f.Z0 = Z0; f.HXS = HXSdec;
                finish0_kernel<<<dim3(512), 256, 0, stream>>>(f);
            }
            hopSingle(GP0, HG0);
            n2one(mkN0(tn, di, HXSdec));
            hopDual(h0Px[tn & 1], HA, h1P, HB);
        } else {
            // Final iteration: cell1 only
            rz2one(mkRZ1(t));
            hopSingle(GP1, HG1);
            n2one(mkN1(t));
        }
    }
}

// Round 14
// 2707.524 us; speedup vs baseline: 1.0833x; 1.0833x over previous
//
#include <hip/hip_runtime.h>
#include <math.h>

#define T_IN   12
#define T_OUT  12
#define NB     8192          /* 512 nodes x 16 batch, row id = n*16+b */
#define EPSV   1e-6f

typedef __attribute__((ext_vector_type(8))) short short8;
typedef __attribute__((ext_vector_type(4))) float floatx4;

// ---------------------------------------------------------------------------
// bf16 helpers. P-format: uint = (lo_bf16 << 16) | hi_bf16, value ~ hi + lo.
// ---------------------------------------------------------------------------
__device__ __forceinline__ unsigned short f2bf(float x) {     // RNE (setup packs)
    union { float f; unsigned u; } v; v.f = x;
    unsigned r = v.u + 0x7fffu + ((v.u >> 16) & 1u);
    return (unsigned short)(r >> 16);
}
__device__ __forceinline__ float bf2f(unsigned short h) {
    union { float f; unsigned u; } v; v.u = ((unsigned)h) << 16;
    return v.f;
}
__device__ __forceinline__ unsigned packbf(float v) {         // trunc split (hot path)
    unsigned u = __float_as_uint(v);
    unsigned hu = u & 0xffff0000u;
    float r = v - __uint_as_float(hu);
    unsigned ru = __float_as_uint(r);
    return (ru & 0xffff0000u) | (u >> 16);
}
__device__ __forceinline__ void split2(float v, short& h, short& l) {  // trunc split
    unsigned u = __float_as_uint(v);
    h = (short)(u >> 16);
    float r = v - __uint_as_float(u & 0xffff0000u);
    l = (short)(__float_as_uint(r) >> 16);
}

__device__ __forceinline__ float sigmoid_fast(float x) {
    return 1.0f / (1.0f + __expf(-x));
}
__device__ __forceinline__ float tanh_fast(float x) {
    float e = __expf(2.0f * x);
    return 1.0f - 2.0f / (e + 1.0f);
}

// ---------------------------------------------------------------------------
// Descriptors
// ---------------------------------------------------------------------------
struct HopA {                    // fp32 setup GEMM (W^2 build)
    const float* M[4];
    float* dst0[4];
};

struct HopM {                    // MFMA hop: Y[z] = M[z] @ X, X/Y in P-format
    const unsigned short* Ahi[4]; const unsigned short* Alo[4];
    const unsigned* src0; const unsigned* src1;
    unsigned* dst0[4]; unsigned* dst1[4];
    int tiles0;
};

struct XHopM {                   // MFMA x-hop: fp32 in/out
    const unsigned short* Ahi[4]; const unsigned short* Alo[4];
    const float* X;              // addr = (col>>4)*NB + k*16 + (col&15)
    float* Y;                    // Y[((col>>4)*4+z)*NB + m*16 + (col&15)]
    int ncols;                   // 192 (encoder all-t)
};

struct WPack { const float* w[4]; unsigned short* hi[4]; unsigned short* lo[4]; };

// Merged setup job: sumfill (blocks 0..511), xenc (512..895), lpack (896..1855)
struct Setup {
    const float* A; float* Wf; float* Wb;
    const float* x; float* xenc;
    const float* W[6]; unsigned short* hi[6]; unsigned short* lo[6];
};

struct LinJob {                  // rz-type job
    const unsigned* seg[10]; int nseg;
    const float* sx[5]; int sxrow[5]; int nsx;
    const unsigned short* Wh[2]; const unsigned short* Wl[2];
    const float* WO[2]; const float* bias[2];
    const float* h; unsigned* GP; float* Z;
    float* PR;                   // mode 1 output: gate-stacked preacts
    int mode;                    // 0 = full, 1 = MFMA-only preact
};

struct NJob {                    // n-gate job
    const unsigned* seg[10]; int nseg; int ksplit;
    const float* sx[5]; int sxrow[5]; int nsx;
    const unsigned short* Wh; const unsigned short* Wl;
    const float* WO; const float* bias;
    const float* Zb; const float* hin; float* hout; unsigned* hPout;
    int doProj; const float* Wp; const float* bp; float* out; float* di; int t;
};

struct F0 {                      // decoder finish0 (efficient v2)
    const float* M[4];           // Wf, W2f, Wb, W2b (fp32)
    const float* di;
    const float* PR;             // [2][NB*64] MFMA preacts from rz0big
    const float* WO[2]; const float* bias[2];  // Wr0/Wz0 fp32, br0/bz0
    const float* h0;
    unsigned* GP0; float* Z0; float* HXS;      // HXS[m*NB + row]
};

// ---------------------------------------------------------------------------
// Merged setup kernel: three independent jobs in exclusive block ranges.
// ---------------------------------------------------------------------------
__global__ __launch_bounds__(256) void setup_kernel(Setup s) {
    __shared__ float s1[256], s2[256];
    int bx = blockIdx.x;
    int t = threadIdx.x;
    if (bx < 512) {
        // sumfill: random-walk normalization
        int i = bx;
        float a = s.A[i * 512 + t] + s.A[i * 512 + t + 256];
        float b = s.A[t * 512 + i] + s.A[(t + 256) * 512 + i];
        s1[t] = a; s2[t] = b;
        __syncthreads();
        for (int off = 128; off > 0; off >>= 1) {
            if (t < off) { s1[t] += s1[t + off]; s2[t] += s2[t + off]; }
            __syncthreads();
        }
        float irs = 1.0f / (s1[0] + EPSV);
        float ics = 1.0f / (s2[0] + EPSV);
        for (int j = t; j < 512; j += 256) {
            s.Wf[i * 512 + j] = s.A[i * 512 + j] * irs;
            s.Wb[i * 512 + j] = s.A[j * 512 + i] * ics;
        }
    } else if (bx < 896) {
        // xenc: transpose encoder x slices
        int idx = (bx - 512) * 256 + t;
        int j = idx & 511;
        int b = (idx >> 9) & 15;
        int tt = idx >> 13;
        s.xenc[tt * NB + j * 16 + b] = s.x[(b * T_IN + tt) * 512 + j];
    } else {
        // lpack: all 6 lin weight matrices into B-fragment order
        int bx2 = bx - 896;
        int g = bx2 / 160;
        int nseg = (g < 3) ? 5 : 10;
        int idx = (bx2 % 160) * 256 + t;
        if (idx < nseg * 4096) {
            int j = idx & 7, ln = (idx >> 3) & 15, ntl = (idx >> 7) & 3, O = idx >> 9;
            int sg = O >> 3, o8 = O & 7;
            int base = (g < 3) ? (65 * sg + 1) : (64 * sg);
            int row = base + o8 * 8 + j;
            int col = ntl * 16 + ln;
            float v = s.W[g][(size_t)row * 64 + col];
            unsigned short h = f2bf(v);
            s.hi[g][idx] = h;
            s.lo[g][idx] = f2bf(v - bf2f(h));
        }
    }
}

// fp32 GEMM for the setup-only W^2 = W @ W build. 64x64 tile, 4x4 micro.
__global__ __launch_bounds__(256) void ghop_kernel(HopA a) {
    int z = blockIdx.z;
    const float* Wm = a.M[z];
    const float* X = Wm;
    float* Y = a.dst0[z];
    int col0 = blockIdx.x * 64;
    int row0 = blockIdx.y * 64;
    int tid = threadIdx.x;
    int tx = tid & 15, ty = tid >> 4;
    int kkA = tid & 15, rrA = tid >> 4;
    int ccB = tid & 63, kkB = tid >> 6;

    __shared__ float As[16][68], Bs[16][68];
    float acc[4][4] = {};

    const float* wp = Wm + (row0 + rrA) * 512 + kkA;
    const float* xp = X + (size_t)(col0 + ccB) + (size_t)kkB * 512;

    float ra[4], rb[4];
#pragma unroll
    for (int p = 0; p < 4; ++p) ra[p] = wp[p * 16 * 512];
#pragma unroll
    for (int p = 0; p < 4; ++p) rb[p] = xp[(size_t)(p * 4) * 512];

    for (int k0 = 0; k0 < 512; k0 += 16) {
#pragma unroll
        for (int p = 0; p < 4; ++p) As[kkA][rrA + p * 16] = ra[p];
#pragma unroll
        for (int p = 0; p < 4; ++p) Bs[kkB + p * 4][ccB] = rb[p];
        __syncthreads();
        if (k0 + 16 < 512) {
            int kn = k0 + 16;
#pragma unroll
            for (int p = 0; p < 4; ++p) ra[p] = wp[p * 16 * 512 + kn];
#pragma unroll
            for (int p = 0; p < 4; ++p) rb[p] = xp[(size_t)(kn + p * 4) * 512];
        }
#pragma unroll
        for (int k = 0; k < 16; ++k) {
            const float4 a4 = *(const float4*)&As[k][ty * 4];
            const float4 b4 = *(const float4*)&Bs[k][tx * 4];
            float av[4] = { a4.x, a4.y, a4.z, a4.w };
            float bv[4] = { b4.x, b4.y, b4.z, b4.w };
#pragma unroll
            for (int i = 0; i < 4; ++i)
#pragma unroll
                for (int j = 0; j < 4; ++j)
                    acc[i][j] = fmaf(av[i], bv[j], acc[i][j]);
        }
        __syncthreads();
    }

    int colw = col0 + tx * 4;
#pragma unroll
    for (int i = 0; i < 4; ++i) {
        int row = row0 + ty * 4 + i;
        *(float4*)&Y[(size_t)row * 512 + colw] =
            make_float4(acc[i][0], acc[i][1], acc[i][2], acc[i][3]);
    }
}

// Pack W (512x512 fp32) into A-fragment-contiguous bf16 hi/lo (for hops)
__global__ void wpack_kernel(WPack a) {
    int z = blockIdx.y;
    int idx = blockIdx.x * 256 + threadIdx.x;   // 0..262143
    int m = idx >> 9, k = idx & 511;
    float x = a.w[z][idx];
    unsigned short h = f2bf(x);
    unsigned short l = f2bf(x - bf2f(h));
    int p = (((m >> 4) * 64 + (k >> 3)) * 16 + (m & 15)) * 8 + (k & 7);
    a.hi[z][p] = h;
    a.lo[z][p] = l;
}

// ---------------------------------------------------------------------------
// MFMA hop GEMM (P-format in/out), dual-source.  Block tile (MI*32)m x 64n,
// 4 waves as 2x2, dbuf LDS, 1 barrier per k-chunk.   (R12 proven version.)
// ---------------------------------------------------------------------------
template<int MI>
__global__ __launch_bounds__(256) void hop_mfma(HopM a) {
    int z = blockIdx.z;
    int nt = blockIdx.x;
    const unsigned* X; unsigned* Y; int c0;
    if (nt < a.tiles0) { X = a.src0; Y = a.dst0[z]; c0 = nt * 64; }
    else { X = a.src1; Y = a.dst1[z]; c0 = (nt - a.tiles0) * 64; }
    const unsigned short* Ahi = a.Ahi[z];
    const unsigned short* Alo = a.Alo[z];
    int bm = blockIdx.y * (MI * 32);

    __shared__ unsigned short Bhi_s[2][64][40];
    __shared__ unsigned short Blo_s[2][64][40];

    int tid = threadIdx.x;
    int lane = tid & 63, w = tid >> 6;
    int wm = (w & 1) * (MI * 16), wn = (w >> 1) * 32;
    int ln = lane & 15, quad = lane >> 4;
    int sc = tid & 63, skh = tid >> 6;

    floatx4 acc[MI][2];
#pragma unroll
    for (int mi = 0; mi < MI; ++mi)
#pragma unroll
        for (int ci = 0; ci < 2; ++ci) acc[mi][ci] = (floatx4)0.0f;

    const unsigned* xbase = X + c0 + sc;
    int mtb = (bm + wm) >> 4;

    unsigned uv[8];
#pragma unroll
    for (int j = 0; j < 8; ++j)
        uv[j] = xbase[(size_t)(skh * 8 + j) * 1024];
    {
        short8 h8, l8;
#pragma unroll
        for (int j = 0; j < 8; ++j) {
            h8[j] = (short)(uv[j] & 0xffffu);
            l8[j] = (short)(uv[j] >> 16);
        }
        *(short8*)&Bhi_s[0][sc][skh * 8] = h8;
        *(short8*)&Blo_s[0][sc][skh * 8] = l8;
    }
#pragma unroll
    for (int j = 0; j < 8; ++j)
        uv[j] = xbase[(size_t)(32 + skh * 8 + j) * 1024];

    for (int it = 0; it < 16; ++it) {
        __syncthreads();
        int cur = it & 1;
        if (it + 1 < 16) {
            short8 h8, l8;
#pragma unroll
            for (int j = 0; j < 8; ++j) {
                h8[j] = (short)(uv[j] & 0xffffu);
                l8[j] = (short)(uv[j] >> 16);
            }
            *(short8*)&Bhi_s[cur ^ 1][sc][skh * 8] = h8;
            *(short8*)&Blo_s[cur ^ 1][sc][skh * 8] = l8;
        }
        if (it + 2 < 16) {
            int kn = (it + 2) * 32;
#pragma unroll
            for (int j = 0; j < 8; ++j)
                uv[j] = xbase[(size_t)(kn + skh * 8 + j) * 1024];
        }
        short8 bh[2], bl[2];
#pragma unroll
        for (int ci = 0; ci < 2; ++ci) {
            bh[ci] = *(const short8*)&Bhi_s[cur][wn + ci * 16 + ln][quad * 8];
            bl[ci] = *(const short8*)&Blo_s[cur][wn + ci * 16 + ln][quad * 8];
        }
        int kob = it * 4 + quad;
#pragma unroll
        for (int mi = 0; mi < MI; ++mi) {
            size_t aoff = ((size_t)((mtb + mi) * 64 + kob) * 16 + ln) * 8;
            short8 Ah = *(const short8*)(Ahi + aoff);
            short8 Al = *(const short8*)(Alo + aoff);
#pragma unroll
            for (int ci = 0; ci < 2; ++ci) {
                acc[mi][ci] = __builtin_amdgcn_mfma_f32_16x16x32_bf16(Ah, bh[ci], acc[mi][ci], 0, 0, 0);
                acc[mi][ci] = __builtin_amdgcn_mfma_f32_16x16x32_bf16(Ah, bl[ci], acc[mi][ci], 0, 0, 0);
                acc[mi][ci] = __builtin_amdgcn_mfma_f32_16x16x32_bf16(Al, bh[ci], acc[mi][ci], 0, 0, 0);
            }
        }
    }

#pragma unroll
    for (int mi = 0; mi < MI; ++mi) {
#pragma unroll
        for (int ci = 0; ci < 2; ++ci) {
            int mrow = bm + wm + mi * 16 + quad * 4;
            int col = c0 + wn + ci * 16 + ln;
#pragma unroll
            for (int r = 0; r < 4; ++r)
                Y[(size_t)(mrow + r) * 1024 + col] = packbf(acc[mi][ci][r]);
        }
    }
}

// ---------------------------------------------------------------------------
// MFMA x-hop (setup): fp32 in/out. Block 64m x 64n (LDS version).
// ---------------------------------------------------------------------------
__global__ __launch_bounds__(256) void xhop_mfma(XHopM a) {
    int z = blockIdx.z;
    int c0 = blockIdx.x * 64;
    const unsigned short* Ahi = a.Ahi[z];
    const unsigned short* Alo = a.Alo[z];
    int bm = blockIdx.y * 64;

    __shared__ unsigned short Bhi_s[2][64][40];
    __shared__ unsigned short Blo_s[2][64][40];

    int tid = threadIdx.x;
    int lane = tid & 63, w = tid >> 6;
    int wm = (w & 1) * 32, wn = (w >> 1) * 32;
    int ln = lane & 15, quad = lane >> 4;
    int sc = tid & 63, skh = tid >> 6;

    floatx4 acc[2][2];
#pragma unroll
    for (int mi = 0; mi < 2; ++mi)
#pragma unroll
        for (int ci = 0; ci < 2; ++ci) acc[mi][ci] = (floatx4)0.0f;

    int colS = c0 + sc;
    bool ok = colS < a.ncols;
    const float* xb = a.X + (size_t)(colS >> 4) * NB + (colS & 15);
    int mtb = (bm + wm) >> 4;

    float xv[8];
#pragma unroll
    for (int j = 0; j < 8; ++j)
        xv[j] = ok ? xb[(size_t)(skh * 8 + j) * 16] : 0.0f;
    {
        short8 h8, l8;
#pragma unroll
        for (int j = 0; j < 8; ++j) { short h, l; split2(xv[j], h, l); h8[j] = h; l8[j] = l; }
        *(short8*)&Bhi_s[0][sc][skh * 8] = h8;
        *(short8*)&Blo_s[0][sc][skh * 8] = l8;
    }
#pragma unroll
    for (int j = 0; j < 8; ++j)
        xv[j] = ok ? xb[(size_t)(32 + skh * 8 + j) * 16] : 0.0f;

    for (int it = 0; it < 16; ++it) {
        __syncthreads();
        int cur = it & 1;
        if (it + 1 < 16) {
            short8 h8, l8;
#pragma unroll
            for (int j = 0; j < 8; ++j) { short h, l; split2(xv[j], h, l); h8[j] = h; l8[j] = l; }
            *(short8*)&Bhi_s[cur ^ 1][sc][skh * 8] = h8;
            *(short8*)&Blo_s[cur ^ 1][sc][skh * 8] = l8;
        }
        if (it + 2 < 16) {
            int kn = (it + 2) * 32;
#pragma unroll
            for (int j = 0; j < 8; ++j)
                xv[j] = ok ? xb[(size_t)(kn + skh * 8 + j) * 16] : 0.0f;
        }
        short8 bh[2], bl[2];
#pragma unroll
        for (int ci = 0; ci < 2; ++ci) {
            bh[ci] = *(const short8*)&Bhi_s[cur][wn + ci * 16 + ln][quad * 8];
            bl[ci] = *(const short8*)&Blo_s[cur][wn + ci * 16 + ln][quad * 8];
        }
        int kob = it * 4 + quad;
#pragma unroll
        for (int mi = 0; mi < 2; ++mi) {
            size_t aoff = ((size_t)((mtb + mi) * 64 + kob) * 16 + ln) * 8;
            short8 Ah = *(const short8*)(Ahi + aoff);
            short8 Al = *(const short8*)(Alo + aoff);
#pragma unroll
            for (int ci = 0; ci < 2; ++ci) {
                acc[mi][ci] = __builtin_amdgcn_mfma_f32_16x16x32_bf16(Ah, bh[ci], acc[mi][ci], 0, 0, 0);
                acc[mi][ci] = __builtin_amdgcn_mfma_f32_16x16x32_bf16(Ah, bl[ci], acc[mi][ci], 0, 0, 0);
                acc[mi][ci] = __builtin_amdgcn_mfma_f32_16x16x32_bf16(Al, bh[ci], acc[mi][ci], 0, 0, 0);
            }
        }
    }

#pragma unroll
    for (int mi = 0; mi < 2; ++mi) {
#pragma unroll
        for (int ci = 0; ci < 2; ++ci) {
            int col = c0 + wn + ci * 16 + ln;
            if (col < a.ncols) {
                int mrow = bm + wm + mi * 16 + quad * 4;
                float* yb = a.Y + (size_t)((col >> 4) * 4 + z) * NB + (col & 15);
#pragma unroll
                for (int r = 0; r < 4; ++r)
                    yb[(size_t)(mrow + r) * 16] = acc[mi][ci][r];
            }
        }
    }
}

// ---------------------------------------------------------------------------
// MFMA lin core (ci-split, seg-range): wave computes 16 rows x 32 cols.
// ---------------------------------------------------------------------------
__device__ __forceinline__ void lin_core2(const unsigned* const* segs, int nseg, int s0,
        const unsigned short* __restrict__ Bh, const unsigned short* __restrict__ Bl,
        int row0, int ln, int quad, int cihalf, floatx4 acc[2]) {
    for (int s = 0; s < nseg; ++s) {
        const unsigned* ap = segs[s] + (size_t)(row0 + ln) * 64 + quad * 8;
#pragma unroll
        for (int hh = 0; hh < 2; ++hh) {
            unsigned u[8];
            *(uint4*)&u[0] = *(const uint4*)(ap + hh * 32);
            *(uint4*)&u[4] = *(const uint4*)(ap + hh * 32 + 4);
            short8 Ah, Al;
#pragma unroll
            for (int j = 0; j < 8; ++j) {
                Ah[j] = (short)(u[j] & 0xffffu);
                Al[j] = (short)(u[j] >> 16);
            }
            int O = (s0 + s) * 8 + hh * 4 + quad;
#pragma unroll
            for (int ci = 0; ci < 2; ++ci) {
                int c_abs = cihalf * 2 + ci;
                size_t boff = ((size_t)(O * 4 + c_abs) * 16 + ln) * 8;
                short8 B1 = *(const short8*)(Bh + boff);
                short8 B2 = *(const short8*)(Bl + boff);
                acc[ci] = __builtin_amdgcn_mfma_f32_16x16x32_bf16(Ah, B1, acc[ci], 0, 0, 0);
                acc[ci] = __builtin_amdgcn_mfma_f32_16x16x32_bf16(Al, B1, acc[ci], 0, 0, 0);
                acc[ci] = __builtin_amdgcn_mfma_f32_16x16x32_bf16(Ah, B2, acc[ci], 0, 0, 0);
            }
        }
    }
}

__device__ __forceinline__ void lin_scalar2p(const float* const* sx, const int* sxrow,
        int nsx, const float* __restrict__ WO,
        int row0, int ln, int quad, int cihalf, floatx4 acc[2]) {
    for (int t = 0; t < nsx; ++t) {
        const float* wr = WO + (size_t)sxrow[t] * 64;
        const float* sv = sx[t] + row0 + quad * 4;
#pragma unroll
        for (int rr = 0; rr < 4; ++rr) {
            float v = sv[rr];
#pragma unroll
            for (int ci = 0; ci < 2; ++ci)
                acc[ci][rr] = fmaf(v, wr[(cihalf * 2 + ci) * 16 + ln], acc[ci][rr]);
        }
    }
}

// rz body — inlined per branch so the kernarg struct is accessed directly
// (NO runtime-selected reference: that forced both structs to scratch, R10).
__device__ __forceinline__ void rz_body(const LinJob& J, int bx) {
    int w = threadIdx.x >> 6, lane = threadIdx.x & 63;
    int ln = lane & 15, quad = lane >> 4;
    int row0 = bx * 64 + w * 16;
    int gate = blockIdx.y;
    int cihalf = blockIdx.z;
    floatx4 acc[2];
    acc[0] = (floatx4)0.0f; acc[1] = (floatx4)0.0f;
    lin_core2(J.seg, J.nseg, 0, J.Wh[gate], J.Wl[gate], row0, ln, quad, cihalf, acc);
    if (J.nsx) lin_scalar2p(J.sx, J.sxrow, J.nsx, J.WO[gate], row0, ln, quad, cihalf, acc);
    if (J.mode == 0) {
        const float* bias = J.bias[gate];
#pragma unroll
        for (int ci = 0; ci < 2; ++ci) {
            int col = (cihalf * 2 + ci) * 16 + ln;
            float bv = bias[col];
#pragma unroll
            for (int rr = 0; rr < 4; ++rr) {
                int row = row0 + quad * 4 + rr;
                size_t idx = (size_t)row * 64 + col;
                float sg = sigmoid_fast(acc[ci][rr] + bv);
                if (gate == 0) J.GP[idx] = packbf(sg * J.h[idx]);
                else J.Z[idx] = sg;
            }
        }
    } else {
        float* PRg = J.PR + (size_t)gate * ((size_t)NB * 64);
#pragma unroll
        for (int ci = 0; ci < 2; ++ci) {
            int col = (cihalf * 2 + ci) * 16 + ln;
#pragma unroll
            for (int rr = 0; rr < 4; ++rr) {
                int row = row0 + quad * 4 + rr;
                PRg[(size_t)row * 64 + col] = acc[ci][rr];
            }
        }
    }
}

// r/z gates, up to two jobs per launch: grid (x, 2 gates, 2 cihalf).
__global__ __launch_bounds__(256) void lin_rz2(LinJob j0, LinJob j1, int xsplit) {
    if ((int)blockIdx.x >= xsplit) rz_body(j1, (int)blockIdx.x - xsplit);
    else                           rz_body(j0, (int)blockIdx.x);
}

// n-gate body — same inlining rule as rz_body.
__device__ __forceinline__ void n_body(const NJob& J, int bx) {
    int w = threadIdx.x >> 6, lane = threadIdx.x & 63;
    int ln = lane & 15, quad = lane >> 4;
    int kh = w & 1, cihalf = w >> 1;
    int row0 = bx * 16;
    __shared__ float part[2][2][16][17];
    __shared__ float pr[2][16];
    floatx4 acc[2];
    acc[0] = (floatx4)0.0f; acc[1] = (floatx4)0.0f;
    if (kh == 0) {
        lin_core2(J.seg, J.ksplit, 0, J.Wh, J.Wl, row0, ln, quad, cihalf, acc);
    } else {
        lin_core2(J.seg + J.ksplit, J.nseg - J.ksplit, J.ksplit, J.Wh, J.Wl,
                  row0, ln, quad, cihalf, acc);
        if (J.nsx) lin_scalar2p(J.sx, J.sxrow, J.nsx, J.WO, row0, ln, quad, cihalf, acc);
#pragma unroll
        for (int ci = 0; ci < 2; ++ci)
#pragma unroll
            for (int rr = 0; rr < 4; ++rr)
                part[cihalf][ci][quad * 4 + rr][ln] = acc[ci][rr];
    }
    __syncthreads();
    float p[4] = {0.0f, 0.0f, 0.0f, 0.0f};
    if (kh == 0) {
#pragma unroll
        for (int ci = 0; ci < 2; ++ci) {
            int col = (cihalf * 2 + ci) * 16 + ln;
            float bv = J.bias[col];
            float wpv = J.doProj ? J.Wp[col] : 0.0f;
#pragma unroll
            for (int rr = 0; rr < 4; ++rr) {
                int row = row0 + quad * 4 + rr;
                size_t idx = (size_t)row * 64 + col;
                float pre = acc[ci][rr] + part[cihalf][ci][quad * 4 + rr][ln] + bv;
                float nn = tanh_fast(pre);
                float z = J.Zb[idx];
                float hv = J.hin[idx];
                float o = (1.0f - z) * hv + z * nn;
                J.hout[idx] = o;
                J.hPout[idx] = packbf(o);
                p[rr] = fmaf(o, wpv, p[rr]);
            }
        }
        if (J.doProj) {
#pragma unroll
            for (int rr = 0; rr < 4; ++rr) {
                p[rr] += __shfl_xor(p[rr], 1, 64);
                p[rr] += __shfl_xor(p[rr], 2, 64);
                p[rr] += __shfl_xor(p[rr], 4, 64);
                p[rr] += __shfl_xor(p[rr], 8, 64);
            }
            if (ln == 0) {
#pragma unroll
                for (int rr = 0; rr < 4; ++rr)
                    pr[cihalf][quad * 4 + rr] = p[rr];
            }
        }
    }
    __syncthreads();
    if (J.doProj && kh == 0 && cihalf == 0 && ln == 0) {
        float bpv = J.bp[0];
#pragma unroll
        for (int rr = 0; rr < 4; ++rr) {
            int qr = quad * 4 + rr;
            int row = row0 + qr;
            float y = pr[0][qr] + pr[1][qr] + bpv;
            int n = row >> 4, b = row & 15;
            J.out[(b * T_OUT + J.t) * 512 + n] = y;
            J.di[row] = y;
        }
    }
}

// n gate + GRU update, up to two jobs per launch.
__global__ __launch_bounds__(256) void lin_n2(NJob j0, NJob j1, int xsplit) {
    if ((int)blockIdx.x >= xsplit) n_body(j1, (int)blockIdx.x - xsplit);
    else                           n_body(j0, (int)blockIdx.x);
}

// ---------------------------------------------------------------------------
// Decoder finish0 v2: 512 blocks (one node each).  Phase 1: 4 di-hops per
// node (64 dots, 4-way split-K, 4 accumulators).  Phase 2: rank-5 scalar
// update on rz0big preacts + sigmoid -> GP0/Z0.  Single by-value struct.
// ---------------------------------------------------------------------------
__global__ __launch_bounds__(256) void finish0_kernel(F0 a) {
    int n = blockIdx.x;                 // node; rows n*16 .. n*16+15
    int tid = threadIdx.x;
    __shared__ float hopS[4][16];
    __shared__ float sdi[16];

    // phase 1: hop_m[b] = sum_k M[m][n][k] * di[k*16+b]
    int g = tid >> 2;                   // 0..63 : m*16+b
    int sub = tid & 3;                  // k-quarter
    int m = g >> 4, b = g & 15;
    const float* wrow = a.M[m] + (size_t)n * 512 + sub * 128;
    const float* dv = a.di + (size_t)(sub * 128) * 16 + b;
    float s0 = 0.0f, s1 = 0.0f, s2 = 0.0f, s3 = 0.0f;
#pragma unroll 8
    for (int k = 0; k < 128; k += 4) {
        float4 w4 = *(const float4*)&wrow[k];
        s0 = fmaf(w4.x, dv[(k + 0) * 16], s0);
        s1 = fmaf(w4.y, dv[(k + 1) * 16], s1);
        s2 = fmaf(w4.z, dv[(k + 2) * 16], s2);
        s3 = fmaf(w4.w, dv[(k + 3) * 16], s3);
    }
    float sv = (s0 + s1) + (s2 + s3);
    sv += __shfl_xor(sv, 1, 64);
    sv += __shfl_xor(sv, 2, 64);
    if (sub == 0) {
        hopS[m][b] = sv;
        a.HXS[(size_t)m * NB + n * 16 + b] = sv;
    }
    if (tid < 16) sdi[tid] = a.di[n * 16 + tid];
    __syncthreads();

    // phase 2: 2 gates x 16 rows x 64 cols
    int gate = tid >> 7, col = tid & 63, rh = (tid >> 6) & 1;
    const float* WOg = a.WO[gate];
    float w0c = WOg[col];
    float wmc[4];
#pragma unroll
    for (int mm = 0; mm < 4; ++mm)
        wmc[mm] = WOg[(size_t)(65 * (mm + 1)) * 64 + col];
    float bv = a.bias[gate][col];
    const float* PRg = a.PR + (size_t)gate * ((size_t)NB * 64);
#pragma unroll
    for (int rr = 0; rr < 8; ++rr) {
        int bl = rh * 8 + rr;
        int row = n * 16 + bl;
        size_t idx = (size_t)row * 64 + col;
        float pre = PRg[idx] + bv + sdi[bl] * w0c;
#pragma unroll
        for (int mm = 0; mm < 4; ++mm)
            pre = fmaf(hopS[mm][bl], wmc[mm], pre);
        float sg = sigmoid_fast(pre);
        if (gate == 0) a.GP0[idx] = packbf(sg * a.h0[idx]);
        else a.Z0[idx] = sg;
    }
}

// ---------------------------------------------------------------------------
extern "C" void kernel_launch(void* const* d_in, const int* in_sizes, int n_in,
                              void* d_out, int out_size, void* d_ws, size_t ws_size,
                              hipStream_t stream) {
    (void)in_sizes; (void)n_in; (void)out_size; (void)ws_size;
    const float* x   = (const float*)d_in[0];
    const float* A   = (const float*)d_in[1];
    const float* Wr0 = (const float*)d_in[2];  const float* br0 = (const float*)d_in[3];
    const float* Wz0 = (const float*)d_in[4];  const float* bz0 = (const float*)d_in[5];
    const float* Wn0 = (const float*)d_in[6];  const float* bn0 = (const float*)d_in[7];
    const float* Wr1 = (const float*)d_in[8];  const float* br1 = (const float*)d_in[9];
    const float* Wz1 = (const float*)d_in[10]; const float* bz1 = (const float*)d_in[11];
    const float* Wn1 = (const float*)d_in[12]; const float* bn1 = (const float*)d_in[13];
    const float* Wp  = (const float*)d_in[14]; const float* bp  = (const float*)d_in[15];
    float* out = (float*)d_out;

    float* ws = (float*)d_ws;
    size_t off = 0;
    auto alloc = [&](size_t nf) { float* p = ws + off; off += nf; return p; };
    const size_t NB64 = (size_t)NB * 64;
    float* Wf  = alloc(262144); float* Wb  = alloc(262144);
    float* W2f = alloc(262144); float* W2b = alloc(262144);
    float* xenc = alloc((size_t)T_IN * NB);
    unsigned short* Whi[4]; unsigned short* Wlo[4];
    for (int m = 0; m < 4; ++m) Whi[m] = (unsigned short*)alloc(131072);
    for (int m = 0; m < 4; ++m) Wlo[m] = (unsigned short*)alloc(131072);
    // contiguous zero-init group: h0x[1], h0Px[1], h1, h1P, HAall(4), HBall(4)
    float* zbase = alloc(12 * NB64);
    float* h0x[2]; unsigned* h0Px[2];
    h0x[1]  = zbase;
    h0Px[1] = (unsigned*)(zbase + NB64);
    float* h1 = zbase + 2 * NB64;
    unsigned* h1P = (unsigned*)(zbase + 3 * NB64);
    unsigned* HAall = (unsigned*)(zbase + 4 * NB64);
    unsigned* HBall = (unsigned*)(zbase + 8 * NB64);
    unsigned* HA[4]; unsigned* HB[4]; unsigned* HG0[4]; unsigned* HG1[4];
    for (int m = 0; m < 4; ++m) HA[m] = HAall + m * NB64;
    for (int m = 0; m < 4; ++m) HB[m] = HBall + m * NB64;
    for (int m = 0; m < 4; ++m) HG0[m] = (unsigned*)alloc(NB64);
    for (int m = 0; m < 4; ++m) HG1[m] = (unsigned*)alloc(NB64);
    unsigned* GP0 = (unsigned*)alloc(NB64);
    unsigned* GP1 = (unsigned*)alloc(NB64);
    float* Z0 = alloc(NB64);
    float* Z1 = alloc(NB64);
    h0x[0]  = alloc(NB64);
    h0Px[0] = (unsigned*)alloc(NB64);
    float* PR0 = alloc(2 * NB64);
    float* XHE = alloc((size_t)T_IN * 4 * NB);
    float* HXSdec = alloc(4 * NB);
    float* di = alloc(NB);
    unsigned short* LWh[6]; unsigned short* LWl[6];
    for (int g = 0; g < 3; ++g) { LWh[g] = (unsigned short*)alloc(10240); LWl[g] = (unsigned short*)alloc(10240); }
    for (int g = 3; g < 6; ++g) { LWh[g] = (unsigned short*)alloc(20480); LWl[g] = (unsigned short*)alloc(20480); }

    hipMemsetAsync(zbase, 0, 12 * NB64 * 4, stream);

    { // merged setup: sumfill + xenc + lpack (all independent)
        Setup s;
        s.A = A; s.Wf = Wf; s.Wb = Wb;
        s.x = x; s.xenc = xenc;
        const float* WG[6] = { Wr0, Wz0, Wn0, Wr1, Wz1, Wn1 };
        for (int g = 0; g < 6; ++g) { s.W[g] = WG[g]; s.hi[g] = LWh[g]; s.lo[g] = LWl[g]; }
        setup_kernel<<<dim3(1856), 256, 0, stream>>>(s);
    }
    {
        HopA w2 = {};
        w2.M[0] = Wf; w2.M[1] = Wb;
        w2.dst0[0] = W2f; w2.dst0[1] = W2b;
        ghop_kernel<<<dim3(8, 8, 2), 256, 0, stream>>>(w2);
    }
    {
        WPack p;
        p.w[0] = Wf; p.w[1] = W2f; p.w[2] = Wb; p.w[3] = W2b;
        for (int m = 0; m < 4; ++m) { p.hi[m] = Whi[m]; p.lo[m] = Wlo[m]; }
        wpack_kernel<<<dim3(1024, 4), 256, 0, stream>>>(p);
    }
    {
        XHopM xa = {};
        for (int m = 0; m < 4; ++m) { xa.Ahi[m] = Whi[m]; xa.Alo[m] = Wlo[m]; }
        xa.X = xenc; xa.Y = XHE; xa.ncols = 192;
        xhop_mfma<<<dim3(3, 8, 4), 256, 0, stream>>>(xa);
    }

    // hop launchers (R12 proven config): single MI=1 @1024, dual MI=2 @1024.
    auto hopSingle = [&](const unsigned* s0, unsigned* const* d0) {
        HopM a = {};
        for (int m = 0; m < 4; ++m) { a.Ahi[m] = Whi[m]; a.Alo[m] = Wlo[m]; }
        a.src0 = s0; a.tiles0 = 16;
        for (int m = 0; m < 4; ++m) a.dst0[m] = d0[m];
        hop_mfma<1><<<dim3(16, 16, 4), 256, 0, stream>>>(a);
    };
    auto hopDual = [&](const unsigned* s0, unsigned* const* d0,
                       const unsigned* s1, unsigned* const* d1) {
        HopM a = {};
        for (int m = 0; m < 4; ++m) { a.Ahi[m] = Whi[m]; a.Alo[m] = Wlo[m]; }
        a.src0 = s0; a.tiles0 = 16;
        for (int m = 0; m < 4; ++m) a.dst0[m] = d0[m];
        a.src1 = s1;
        for (int m = 0; m < 4; ++m) a.dst1[m] = d1[m];
        hop_mfma<2><<<dim3(32, 8, 4), 256, 0, stream>>>(a);
    };

    auto mkRZ1 = [&](int t) {
        LinJob J = {};
        J.seg[0] = h0Px[t & 1]; J.seg[1] = h1P;
        for (int m = 0; m < 4; ++m) { J.seg[2 + 2 * m] = HA[m]; J.seg[3 + 2 * m] = HB[m]; }
        J.nseg = 10; J.nsx = 0;
        J.Wh[0] = LWh[3]; J.Wl[0] = LWl[3]; J.Wh[1] = LWh[4]; J.Wl[1] = LWl[4];
        J.WO[0] = Wr1; J.WO[1] = Wz1; J.bias[0] = br1; J.bias[1] = bz1;
        J.h = h1; J.GP = GP1; J.Z = Z1; J.mode = 0;
        return J;
    };
    auto mkRZ0 = [&](int tn, const float* xc, const float* hx, int mode) {
        LinJob J = {};
        J.seg[0] = h0Px[(tn - 1) & 1];
        for (int m = 0; m < 4; ++m) J.seg[1 + m] = HA[m];
        J.nseg = 5;
        if (mode == 0) {
            J.nsx = 5;
            J.sx[0] = xc; J.sxrow[0] = 0;
            for (int m = 0; m < 4; ++m) { J.sx[1 + m] = hx + (size_t)m * NB; J.sxrow[1 + m] = 65 * (m + 1); }
        }
        J.Wh[0] = LWh[0]; J.Wl[0] = LWl[0]; J.Wh[1] = LWh[1]; J.Wl[1] = LWl[1];
        J.WO[0] = Wr0; J.WO[1] = Wz0; J.bias[0] = br0; J.bias[1] = bz0;
        J.h = h0x[(tn - 1) & 1]; J.GP = GP0; J.Z = Z0; J.PR = PR0; J.mode = mode;
        return J;
    };
    auto mkN1 = [&](int t) {
        NJob J = {};
        J.seg[0] = h0Px[t & 1]; J.seg[1] = GP1;
        for (int m = 0; m < 4; ++m) { J.seg[2 + 2 * m] = HA[m]; J.seg[3 + 2 * m] = HG1[m]; }
        J.nseg = 10; J.ksplit = 5; J.nsx = 0;
        J.Wh = LWh[5]; J.Wl = LWl[5]; J.WO = Wn1; J.bias = bn1;
        J.Zb = Z1; J.hin = h1; J.hout = h1; J.hPout = h1P;
        J.doProj = (t >= T_IN); J.Wp = Wp; J.bp = bp; J.out = out; J.di = di; J.t = t - T_IN;
        return J;
    };
    auto mkN0 = [&](int tn, const float* xc, const float* hx) {
        NJob J = {};
        J.seg[0] = GP0;
        for (int m = 0; m < 4; ++m) J.seg[1 + m] = HG0[m];
        J.nseg = 5; J.ksplit = 3;
        J.nsx = 5;
        J.sx[0] = xc; J.sxrow[0] = 0;
        for (int m = 0; m < 4; ++m) { J.sx[1 + m] = hx + (size_t)m * NB; J.sxrow[1 + m] = 65 * (m + 1); }
        J.Wh = LWh[2]; J.Wl = LWl[2]; J.WO = Wn0; J.bias = bn0;
        J.Zb = Z0; J.hin = h0x[(tn - 1) & 1]; J.hout = h0x[tn & 1]; J.hPout = h0Px[tn & 1];
        J.doProj = 0;
        return J;
    };

    auto rz2one = [&](LinJob a) { lin_rz2<<<dim3(128, 2, 2), 256, 0, stream>>>(a, a, 128); };
    auto rz2two = [&](LinJob a, LinJob b) { lin_rz2<<<dim3(256, 2, 2), 256, 0, stream>>>(a, b, 128); };
    auto n2one = [&](NJob a) { lin_n2<<<dim3(512), 256, 0, stream>>>(a, a, 512); };
    auto n2two = [&](NJob a, NJob b) { lin_n2<<<dim3(1024), 256, 0, stream>>>(a, b, 512); };

    // ---- prologue: cell0 of step 0 -----------------------------------------
    rz2one(mkRZ0(0, xenc, XHE, 0));
    hopSingle(GP0, HG0);
    n2one(mkN0(0, xenc, XHE));
    hopSingle(h0Px[0], HA);

    // ---- main loop: iter t = (cell1 of t) + (cell0 of t+1) -----------------
    for (int t = 0; t < T_IN + T_OUT; ++t) {
        int tn = t + 1;
        bool last = (t == T_IN + T_OUT - 1);
        bool decFeed = (tn >= T_IN + 1);   // cell0(tn) needs di from n1(t)
        if (!last && !decFeed) {
            // Encoder-style paired iteration (x for cell0(tn) known upfront)
            int ts = (tn < T_IN) ? tn : (T_IN - 1);
            const float* xc = xenc + (size_t)ts * NB;
            const float* hx = XHE + (size_t)ts * 4 * NB;
            rz2two(mkRZ1(t), mkRZ0(tn, xc, hx, 0));
            hopDual(GP1, HG1, GP0, HG0);
            n2two(mkN1(t), mkN0(tn, xc, hx));
            hopDual(h0Px[tn & 1], HA, h1P, HB);
        } else if (!last) {
            // Decoder iteration: rz0's MFMA part is di-independent -> pair it.
            rz2two(mkRZ1(t), mkRZ0(tn, nullptr, nullptr, 1));
            hopSingle(GP1, HG1);
            n2one(mkN1(t));                       // writes di, out[t-T_IN]
            {
                F0 f = {};
                f.M[0] = Wf; f.M[1] = W2f; f.M[2] = Wb; f.M[3] = W2b;
                f.di = di; f.PR = PR0;
                f.WO[0] = Wr0; f.WO[1] = Wz0; f.bias[0] = br0; f.bias[1] = bz0;
                f.h0 = h0x[t & 1];
                f.GP0 = GP0; f.Z0 = Z0; f.HXS = HXSdec;
                finish0_kernel<<<dim3(512), 256, 0, stream>>>(f);
            }
            hopSingle(GP0, HG0);
            n2one(mkN0(tn, di, HXSdec));
            hopDual(h0Px[tn & 1], HA, h1P, HB);
        } else {
            // Final iteration: cell1 only
            rz2one(mkRZ1(t));
            hopSingle(GP1, HG1);
            n2one(mkN1(t));
        }
    }
}